// Round 1
// baseline (257.431 us; speedup 1.0000x reference)
//
#include <hip/hip_runtime.h>

#define DEVI __device__ __forceinline__

typedef __bf16 bf16x8 __attribute__((ext_vector_type(8)));
typedef float  f32x4  __attribute__((ext_vector_type(4)));
typedef unsigned short u16;

// ---------- helpers ----------
static DEVI u16 f2bf(float f){                 // fp32 -> bf16 RNE
  unsigned u = __builtin_bit_cast(unsigned, f);
  u += 0x7fffu + ((u >> 16) & 1u);
  return (u16)(u >> 16);
}

static DEVI f32x4 mfma16(bf16x8 a, bf16x8 b, f32x4 c){
  return __builtin_amdgcn_mfma_f32_16x16x32_bf16(a, b, c, 0, 0, 0);
}

static DEVI void gload_lds16(const void* g, void* l){
  __builtin_amdgcn_global_load_lds((const __attribute__((address_space(1))) unsigned int*)g,
                                   (__attribute__((address_space(3))) unsigned int*)l,
                                   16, 0, 0);
}

// ---------- 1) fp32 -> bf16 conversion of x, Wqkv, Wout ----------
__global__ void convert_kernel(const float* __restrict__ x, const float* __restrict__ wq,
                               const float* __restrict__ wo,
                               u16* __restrict__ xb, u16* __restrict__ wqb, u16* __restrict__ wob){
  const int NX = 2048*1024, NQ = 3072*1024, NW = 1024*1024;
  const int total4 = (NX + NQ + NW) / 4;
  for (int i = blockIdx.x*blockDim.x + threadIdx.x; i < total4; i += gridDim.x*blockDim.x){
    int e = i * 4;
    const float* src; u16* dst; int off;
    if (e < NX)           { src = x;  dst = xb;  off = e; }
    else if (e < NX + NQ) { src = wq; dst = wqb; off = e - NX; }
    else                  { src = wo; dst = wob; off = e - NX - NQ; }
    float4 v = *(const float4*)(src + off);
    ushort4 o;
    o.x = f2bf(v.x); o.y = f2bf(v.y); o.z = f2bf(v.z); o.w = f2bf(v.w);
    *(ushort4*)(dst + off) = o;
  }
}

// ---------- 2/5) GEMM  C[M,N] = A[M,K] * B[N,K]^T  (bf16 in, fp32 acc) ----------
// 128x128 tile, BK=64, 512 threads (8 waves, 2x4), mfma 16x16x32 bf16.
// LDS XOR-swizzle: byte_in_row ^= (row&7)<<4, applied by pre-swizzling the
// global source (LDS dest of global_load_lds must stay linear) and on ds_read.
// EPI==0: plain fp32 C (ldc). EPI==1: qkv scatter (q,k -> fp32 ws; v -> bf16 v_t[h][d][s]).
template<int EPI>
__global__ __launch_bounds__(512, 1)
void gemm_bt(const u16* __restrict__ A, const u16* __restrict__ B, int K,
             float* __restrict__ C, int ldc,
             u16* __restrict__ v_t, float* __restrict__ qkf){
  __shared__ u16 As[128*64];
  __shared__ u16 Bs[128*64];
  const int tid  = threadIdx.x;
  const int lane = tid & 63;
  const int wid  = tid >> 6;
  const int wr   = wid >> 2, wc = wid & 3;      // wave -> 64x32 sub-tile
  const int l15  = lane & 15, lg = lane >> 4;
  const int bm   = blockIdx.y * 128, bn = blockIdx.x * 128;

  // staging: 1024 16B chunks per tile, 2 per thread. chunk c -> LDS byte c*16,
  // logical (row=c/8, colbyte=(c&7)*16); global colbyte = colbyte ^ ((row&7)<<4).
  const int c0 = tid, c1 = tid + 512;
  const int r0 = c0 >> 3, r1 = c1 >> 3;
  const int gb0 = ((c0 & 7) << 4) ^ ((r0 & 7) << 4);
  const int gb1 = ((c1 & 7) << 4) ^ ((r1 & 7) << 4);
  const u16* Ag0 = A + (size_t)(bm + r0) * K + (gb0 >> 1);
  const u16* Ag1 = A + (size_t)(bm + r1) * K + (gb1 >> 1);
  const u16* Bg0 = B + (size_t)(bn + r0) * K + (gb0 >> 1);
  const u16* Bg1 = B + (size_t)(bn + r1) * K + (gb1 >> 1);

  // per-lane fragment read bases (swizzled ds_read_b128)
  int baseA[4], swzA[4], baseB[2], swzB[2];
  #pragma unroll
  for (int m = 0; m < 4; ++m){
    int r = wr*64 + m*16 + l15;
    baseA[m] = r * 128; swzA[m] = (r & 7) << 4;
  }
  #pragma unroll
  for (int n = 0; n < 2; ++n){
    int r = wc*32 + n*16 + l15;
    baseB[n] = r * 128; swzB[n] = (r & 7) << 4;
  }
  const int colb = lg * 16;

  f32x4 acc[4][2] = {};
  const char* Ab = (const char*)As;
  const char* Bb = (const char*)Bs;

  for (int kb = 0; kb < K; kb += 64){
    gload_lds16(Ag0 + kb, &As[c0 * 8]);
    gload_lds16(Ag1 + kb, &As[c1 * 8]);
    gload_lds16(Bg0 + kb, &Bs[c0 * 8]);
    gload_lds16(Bg1 + kb, &Bs[c1 * 8]);
    __syncthreads();
    #pragma unroll
    for (int kk = 0; kk < 2; ++kk){
      bf16x8 av[4], bv[2];
      #pragma unroll
      for (int m = 0; m < 4; ++m)
        av[m] = *(const bf16x8*)(Ab + baseA[m] + ((kk*64 + colb) ^ swzA[m]));
      #pragma unroll
      for (int n = 0; n < 2; ++n)
        bv[n] = *(const bf16x8*)(Bb + baseB[n] + ((kk*64 + colb) ^ swzB[n]));
      #pragma unroll
      for (int m = 0; m < 4; ++m)
        #pragma unroll
        for (int n = 0; n < 2; ++n)
          acc[m][n] = mfma16(av[m], bv[n], acc[m][n]);
    }
    __syncthreads();
  }

  // epilogue. C/D layout: col = lane&15, row = (lane>>4)*4 + reg  [m89-verified]
  #pragma unroll
  for (int m = 0; m < 4; ++m){
    const int srow = bm + wr*64 + m*16 + lg*4;
    #pragma unroll
    for (int n = 0; n < 2; ++n){
      const int f = bn + wc*32 + n*16 + l15;
      f32x4 v = acc[m][n];
      if (EPI == 0){
        #pragma unroll
        for (int r = 0; r < 4; ++r)
          C[(size_t)(srow + r)*ldc + f] = v[r];
      } else {
        const int which = f >> 10, rem = f & 1023;
        const int h = rem >> 6, d = rem & 63;
        if (which == 2){
          // v: straight to bf16, transposed layout v_t[h][d][s]
          ushort4 p;
          p.x = f2bf(v[0]); p.y = f2bf(v[1]); p.z = f2bf(v[2]); p.w = f2bf(v[3]);
          *(ushort4*)(v_t + ((size_t)(h*64 + d))*2048 + srow) = p;
        } else {
          // q/k: fp32 staging buffer [2][16][2048][64] for RoPE
          float* dst = qkf + (((size_t)(which*16 + h))*2048 + srow)*64 + d;
          #pragma unroll
          for (int r = 0; r < 4; ++r) dst[(size_t)r * 64] = v[r];
        }
      }
    }
  }
}

// ---------- 3) RoPE on q,k (fp32 in, bf16 out) ----------
// NOTE this reference's variant: pair (2i,2i+1) uses inv_freq[(2i)%32] and
// inv_freq[(2i+1)%32] (different frequencies per pair element).
__global__ void rope_kernel(const float* __restrict__ qkf,
                            u16* __restrict__ q_r, u16* __restrict__ k_r){
  const int t = blockIdx.x*blockDim.x + threadIdx.x;   // 2^21 threads exactly
  const int i = t & 31;
  const int s = (t >> 5) & 2047;
  const int h = (t >> 16) & 15;
  const int w = t >> 20;
  const float2 xv = *(const float2*)(qkf + (((size_t)w*16 + h)*2048 + s)*64 + 2*i);
  const int idx0 = (2*i) & 31;
  const float NEGL = -0.41524101186091903f;            // -log2(10000)/32
  const float f0 = exp2f(NEGL * (float)idx0);
  const float f1 = exp2f(NEGL * (float)(idx0 + 1));
  const float a0 = (float)s * f0, a1 = (float)s * f1;
  float s0, c0, s1, c1;
  sincosf(a0, &s0, &c0);
  sincosf(a1, &s1, &c1);
  const float o0 = xv.x * c0 - xv.y * s0;              // x0*cos - x1*sin
  const float o1 = xv.y * c1 + xv.x * s1;              // x1*cos + x0*sin
  u16* dst = (w == 0 ? q_r : k_r) + ((size_t)h*2048 + s)*64 + 2*i;
  ushort2 pr; pr.x = f2bf(o0); pr.y = f2bf(o1);
  *(ushort2*)dst = pr;
}

// ---------- 4) causal flash attention ----------
// 1 wave per (16 q-rows, head). Q in regs; K/V fragments straight from
// global (L2-resident); P through per-wave LDS to re-lay as A-fragment.
__global__ __launch_bounds__(64, 1)
void attn_kernel(const u16* __restrict__ q_r, const u16* __restrict__ k_r,
                 const u16* __restrict__ v_t, u16* __restrict__ ao){
  __shared__ u16 P[16*32];
  const int lane = threadIdx.x;
  const int l15 = lane & 15, lg = lane >> 4;
  const int h  = blockIdx.y;
  const int q0 = ((int)gridDim.x - 1 - (int)blockIdx.x) * 16;  // longest blocks first

  bf16x8 qf[2];
  #pragma unroll
  for (int kk = 0; kk < 2; ++kk)
    qf[kk] = *(const bf16x8*)(q_r + ((size_t)h*2048 + q0 + l15)*64 + kk*32 + lg*8);

  f32x4 o[4] = {};
  float m[4], l[4];
  #pragma unroll
  for (int r = 0; r < 4; ++r){ m[r] = -3.0e38f; l[r] = 0.f; }

  const int nkb = (q0 + 15)/32 + 1;
  for (int ib = 0; ib < nkb; ++ib){
    const int kb = ib * 32;
    // S = Q K^T  (per-wave 16x32)
    f32x4 s[2] = {};
    #pragma unroll
    for (int ct = 0; ct < 2; ++ct)
      #pragma unroll
      for (int kk = 0; kk < 2; ++kk){
        bf16x8 kf = *(const bf16x8*)(k_r + ((size_t)h*2048 + kb + ct*16 + l15)*64 + kk*32 + lg*8);
        s[ct] = mfma16(qf[kk], kf, s[ct]);
      }
    // scale + causal mask (only diagonal-adjacent blocks can mask)
    const bool maskb = (kb + 31 > q0);
    #pragma unroll
    for (int ct = 0; ct < 2; ++ct){
      const int key = kb + ct*16 + l15;
      #pragma unroll
      for (int r = 0; r < 4; ++r){
        float sv = s[ct][r] * 0.125f;
        if (maskb && key > (q0 + lg*4 + r)) sv = -3.0e38f;
        s[ct][r] = sv;
      }
    }
    // online softmax (fp32); row lives in the 16 lanes sharing lg
    float sc[4];
    #pragma unroll
    for (int r = 0; r < 4; ++r){
      float v = fmaxf(s[0][r], s[1][r]);
      #pragma unroll
      for (int off = 1; off < 16; off <<= 1) v = fmaxf(v, __shfl_xor(v, off));
      const float mn = fmaxf(m[r], v);
      sc[r] = expf(m[r] - mn);
      m[r] = mn;
    }
    float rs[4] = {0.f, 0.f, 0.f, 0.f};
    #pragma unroll
    for (int ct = 0; ct < 2; ++ct)
      #pragma unroll
      for (int r = 0; r < 4; ++r){
        const float p = expf(s[ct][r] - m[r]);
        s[ct][r] = p;
        rs[r] += p;
      }
    #pragma unroll
    for (int r = 0; r < 4; ++r){
      float v = rs[r];
      #pragma unroll
      for (int off = 1; off < 16; off <<= 1) v += __shfl_xor(v, off);
      l[r] = l[r]*sc[r] + v;
    }
    #pragma unroll
    for (int dt = 0; dt < 4; ++dt)
      #pragma unroll
      for (int r = 0; r < 4; ++r) o[dt][r] *= sc[r];
    // P (C-layout) -> LDS -> A-fragment layout
    #pragma unroll
    for (int ct = 0; ct < 2; ++ct)
      #pragma unroll
      for (int r = 0; r < 4; ++r)
        P[(lg*4 + r)*32 + ct*16 + l15] = f2bf(s[ct][r]);
    asm volatile("s_waitcnt lgkmcnt(0)" ::: "memory");
    const bf16x8 pf = *(const bf16x8*)((const char*)P + (l15*32 + lg*8)*2);
    #pragma unroll
    for (int dt = 0; dt < 4; ++dt){
      bf16x8 vf = *(const bf16x8*)(v_t + ((size_t)h*64 + dt*16 + l15)*2048 + kb + lg*8);
      o[dt] = mfma16(pf, vf, o[dt]);
    }
  }
  float inv[4];
  #pragma unroll
  for (int r = 0; r < 4; ++r) inv[r] = 1.0f / l[r];
  // write attention out in (s, h*64+d) layout = A-matrix of the final GEMM
  #pragma unroll
  for (int dt = 0; dt < 4; ++dt)
    #pragma unroll
    for (int r = 0; r < 4; ++r)
      ao[(size_t)(q0 + lg*4 + r)*1024 + h*64 + dt*16 + l15] = f2bf(o[dt][r] * inv[r]);
}

// ---------- launch ----------
extern "C" void kernel_launch(void* const* d_in, const int* in_sizes, int n_in,
                              void* d_out, int out_size, void* d_ws, size_t ws_size,
                              hipStream_t stream) {
  const float* x  = (const float*)d_in[0];   // (1,2048,1024)
  const float* wq = (const float*)d_in[1];   // (3072,1024)
  const float* wo = (const float*)d_in[2];   // (1024,1024)
  float* out = (float*)d_out;                // (1,2048,1024) fp32

  char* w = (char*)d_ws;                     // 44 MB used
  u16*   xb  = (u16*)(w + (size_t) 0);        // 4 MB  x bf16
  u16*   wqb = (u16*)(w + (size_t)( 4<<20));  // 6 MB  Wqkv bf16
  u16*   wob = (u16*)(w + (size_t)(10<<20));  // 2 MB  Wout bf16
  u16*   q_r = (u16*)(w + (size_t)(12<<20));  // 4 MB  q roped bf16 [16][2048][64]
  u16*   k_r = (u16*)(w + (size_t)(16<<20));  // 4 MB  k roped bf16 [16][2048][64]
  u16*   v_t = (u16*)(w + (size_t)(20<<20));  // 4 MB  v bf16 transposed [16][64][2048]
  u16*   ao  = (u16*)(w + (size_t)(24<<20));  // 4 MB  attn out bf16 [2048][1024]
  float* qkf = (float*)(w + (size_t)(28<<20)); // 16 MB q,k fp32 [2][16][2048][64]

  convert_kernel<<<2048, 256, 0, stream>>>(x, wq, wo, xb, wqb, wob);
  gemm_bt<1><<<dim3(24, 16), 512, 0, stream>>>(xb, wqb, 1024, nullptr, 0, v_t, qkf);
  rope_kernel<<<8192, 256, 0, stream>>>(qkf, q_r, k_r);
  attn_kernel<<<dim3(128, 16), 64, 0, stream>>>(q_r, k_r, v_t, ao);
  gemm_bt<0><<<dim3(8, 16), 512, 0, stream>>>(ao, wob, 1024, out, 1024, nullptr, nullptr);
}

// Round 5
// 189.275 us; speedup vs baseline: 1.3601x; 1.3601x over previous
//
#include <hip/hip_runtime.h>

#define DEVI __device__ __forceinline__

typedef __bf16 bf16x8 __attribute__((ext_vector_type(8)));
typedef float  f32x4  __attribute__((ext_vector_type(4)));
typedef unsigned short u16;

// ---------- helpers ----------
static DEVI u16 f2bf(float f){                 // fp32 -> bf16 RNE
  unsigned u = __builtin_bit_cast(unsigned, f);
  u += 0x7fffu + ((u >> 16) & 1u);
  return (u16)(u >> 16);
}

static DEVI f32x4 mfma16(bf16x8 a, bf16x8 b, f32x4 c){
  return __builtin_amdgcn_mfma_f32_16x16x32_bf16(a, b, c, 0, 0, 0);
}

static DEVI void gload_lds16(const void* g, void* l){
  __builtin_amdgcn_global_load_lds((const __attribute__((address_space(1))) unsigned int*)g,
                                   (__attribute__((address_space(3))) unsigned int*)l,
                                   16, 0, 0);
}

// ---------- 1) fp32 -> bf16 conversion of x, Wqkv, Wout ----------
__global__ void convert_kernel(const float* __restrict__ x, const float* __restrict__ wq,
                               const float* __restrict__ wo,
                               u16* __restrict__ xb, u16* __restrict__ wqb, u16* __restrict__ wob){
  const int NX = 2048*1024, NQ = 3072*1024, NW = 1024*1024;
  const int total4 = (NX + NQ + NW) / 4;
  for (int i = blockIdx.x*blockDim.x + threadIdx.x; i < total4; i += gridDim.x*blockDim.x){
    int e = i * 4;
    const float* src; u16* dst; int off;
    if (e < NX)           { src = x;  dst = xb;  off = e; }
    else if (e < NX + NQ) { src = wq; dst = wqb; off = e - NX; }
    else                  { src = wo; dst = wob; off = e - NX - NQ; }
    float4 v = *(const float4*)(src + off);
    ushort4 o;
    o.x = f2bf(v.x); o.y = f2bf(v.y); o.z = f2bf(v.z); o.w = f2bf(v.w);
    *(ushort4*)(dst + off) = o;
  }
}

// ---------- 2/5) GEMM  C[M,N] = A[M,K] * B[N,K]^T  (bf16 in, fp32 acc) ----------
template<int EPI>
__global__ __launch_bounds__(512, 1)
void gemm_bt(const u16* __restrict__ A, const u16* __restrict__ B, int K,
             float* __restrict__ C, int ldc,
             u16* __restrict__ v_t, float* __restrict__ qkf){
  __shared__ u16 As[128*64];
  __shared__ u16 Bs[128*64];
  const int tid  = threadIdx.x;
  const int lane = tid & 63;
  const int wid  = tid >> 6;
  const int wr   = wid >> 2, wc = wid & 3;      // wave -> 64x32 sub-tile
  const int l15  = lane & 15, lg = lane >> 4;
  const int bm   = blockIdx.y * 128, bn = blockIdx.x * 128;

  const int c0 = tid, c1 = tid + 512;
  const int r0 = c0 >> 3, r1 = c1 >> 3;
  const int gb0 = ((c0 & 7) << 4) ^ ((r0 & 7) << 4);
  const int gb1 = ((c1 & 7) << 4) ^ ((r1 & 7) << 4);
  const u16* Ag0 = A + (size_t)(bm + r0) * K + (gb0 >> 1);
  const u16* Ag1 = A + (size_t)(bm + r1) * K + (gb1 >> 1);
  const u16* Bg0 = B + (size_t)(bn + r0) * K + (gb0 >> 1);
  const u16* Bg1 = B + (size_t)(bn + r1) * K + (gb1 >> 1);

  int baseA[4], swzA[4], baseB[2], swzB[2];
  #pragma unroll
  for (int m = 0; m < 4; ++m){
    int r = wr*64 + m*16 + l15;
    baseA[m] = r * 128; swzA[m] = (r & 7) << 4;
  }
  #pragma unroll
  for (int n = 0; n < 2; ++n){
    int r = wc*32 + n*16 + l15;
    baseB[n] = r * 128; swzB[n] = (r & 7) << 4;
  }
  const int colb = lg * 16;

  f32x4 acc[4][2] = {};
  const char* Ab = (const char*)As;
  const char* Bb = (const char*)Bs;

  for (int kb = 0; kb < K; kb += 64){
    gload_lds16(Ag0 + kb, &As[c0 * 8]);
    gload_lds16(Ag1 + kb, &As[c1 * 8]);
    gload_lds16(Bg0 + kb, &Bs[c0 * 8]);
    gload_lds16(Bg1 + kb, &Bs[c1 * 8]);
    __syncthreads();
    #pragma unroll
    for (int kk = 0; kk < 2; ++kk){
      bf16x8 av[4], bv[2];
      #pragma unroll
      for (int m = 0; m < 4; ++m)
        av[m] = *(const bf16x8*)(Ab + baseA[m] + ((kk*64 + colb) ^ swzA[m]));
      #pragma unroll
      for (int n = 0; n < 2; ++n)
        bv[n] = *(const bf16x8*)(Bb + baseB[n] + ((kk*64 + colb) ^ swzB[n]));
      #pragma unroll
      for (int m = 0; m < 4; ++m)
        #pragma unroll
        for (int n = 0; n < 2; ++n)
          acc[m][n] = mfma16(av[m], bv[n], acc[m][n]);
    }
    __syncthreads();
  }

  #pragma unroll
  for (int m = 0; m < 4; ++m){
    const int srow = bm + wr*64 + m*16 + lg*4;
    #pragma unroll
    for (int n = 0; n < 2; ++n){
      const int f = bn + wc*32 + n*16 + l15;
      f32x4 v = acc[m][n];
      if (EPI == 0){
        #pragma unroll
        for (int r = 0; r < 4; ++r)
          C[(size_t)(srow + r)*ldc + f] = v[r];
      } else {
        const int which = f >> 10, rem = f & 1023;
        const int h = rem >> 6, d = rem & 63;
        if (which == 2){
          ushort4 p;
          p.x = f2bf(v[0]); p.y = f2bf(v[1]); p.z = f2bf(v[2]); p.w = f2bf(v[3]);
          *(ushort4*)(v_t + ((size_t)(h*64 + d))*2048 + srow) = p;
        } else {
          float* dst = qkf + (((size_t)(which*16 + h))*2048 + srow)*64 + d;
          #pragma unroll
          for (int r = 0; r < 4; ++r) dst[(size_t)r * 64] = v[r];
        }
      }
    }
  }
}

// ---------- 3) RoPE on q,k (fp32 in, bf16 out) ----------
__global__ void rope_kernel(const float* __restrict__ qkf,
                            u16* __restrict__ q_r, u16* __restrict__ k_r){
  const int t = blockIdx.x*blockDim.x + threadIdx.x;   // 2^21 threads exactly
  const int i = t & 31;
  const int s = (t >> 5) & 2047;
  const int h = (t >> 16) & 15;
  const int w = t >> 20;
  const float2 xv = *(const float2*)(qkf + (((size_t)w*16 + h)*2048 + s)*64 + 2*i);
  const int idx0 = (2*i) & 31;
  const float NEGL = -0.41524101186091903f;            // -log2(10000)/32
  const float f0 = exp2f(NEGL * (float)idx0);
  const float f1 = exp2f(NEGL * (float)(idx0 + 1));
  const float a0 = (float)s * f0, a1 = (float)s * f1;
  float s0, c0, s1, c1;
  sincosf(a0, &s0, &c0);
  sincosf(a1, &s1, &c1);
  const float o0 = xv.x * c0 - xv.y * s0;
  const float o1 = xv.y * c1 + xv.x * s1;
  u16* dst = (w == 0 ? q_r : k_r) + ((size_t)h*2048 + s)*64 + 2*i;
  ushort2 pr; pr.x = f2bf(o0); pr.y = f2bf(o1);
  *(ushort2*)dst = pr;
}

// ---------- 4) causal flash attention ----------
// 4 waves/block, QBLK=64 (16 q-rows per wave), KB=64.
// K/V double-buffered in LDS via global_load_lds (cooperative, XOR-swizzled).
// Per-wave P through swizzled LDS. Longest tiles launched first.
static DEVI void stage_kv(const u16* __restrict__ kg, const u16* __restrict__ vg,
                          u16* Ks, u16* Vs, int tid){
  #pragma unroll
  for (int i = 0; i < 2; ++i){
    const int c = tid + i*256;
    const int row = c >> 3;
    const int cb = ((c & 7) << 4) ^ ((row & 7) << 4);
    gload_lds16(kg + (size_t)row*64   + (cb >> 1), Ks + c*8);
    gload_lds16(vg + (size_t)row*2048 + (cb >> 1), Vs + c*8);
  }
}

__global__ __launch_bounds__(256)
void attn_kernel(const u16* __restrict__ q_r, const u16* __restrict__ k_r,
                 const u16* __restrict__ v_t, u16* __restrict__ ao){
  __shared__ u16 Ks[2][64*64];
  __shared__ u16 Vs[2][64*64];
  __shared__ u16 P[4][16*64];
  const int tid  = threadIdx.x;
  const int lane = tid & 63, w = tid >> 6;
  const int l15  = lane & 15, lg = lane >> 4;
  const int h    = blockIdx.y;
  const int tile = (int)gridDim.x - 1 - (int)blockIdx.x;  // longest first
  const int q0   = tile * 64;
  const int qb   = q0 + w*16;           // wave's q-row base
  const int nt   = tile + 1;            // number of 64-key tiles

  const u16* kg = k_r + (size_t)h*2048*64;
  const u16* vg = v_t + (size_t)h*64*2048;

  bf16x8 qf[2];
  #pragma unroll
  for (int kk = 0; kk < 2; ++kk)
    qf[kk] = *(const bf16x8*)(q_r + ((size_t)h*2048 + qb + l15)*64 + kk*32 + lg*8);

  f32x4 o[4] = {};
  float m[4], l[4];
  #pragma unroll
  for (int r = 0; r < 4; ++r){ m[r] = -3.0e38f; l[r] = 0.f; }

  stage_kv(kg, vg, &Ks[0][0], &Vs[0][0], tid);
  asm volatile("s_waitcnt vmcnt(0)" ::: "memory");
  __syncthreads();

  int cur = 0;
  for (int ib = 0; ib < nt; ++ib){
    const int kb = ib * 64;
    if (ib + 1 < nt)
      stage_kv(kg + (size_t)(kb + 64)*64, vg + (kb + 64), &Ks[cur^1][0], &Vs[cur^1][0], tid);

    // ---- S = Q K^T (16 q-rows x 64 keys) ----
    f32x4 s[4] = {};
    const char* Kb = (const char*)&Ks[cur][0];
    #pragma unroll
    for (int ct = 0; ct < 4; ++ct){
      const int row = ct*16 + l15;
      const int swz = (row & 7) << 4;
      #pragma unroll
      for (int kk = 0; kk < 2; ++kk){
        bf16x8 kf = *(const bf16x8*)(Kb + row*128 + ((kk*64 + lg*16) ^ swz));
        s[ct] = mfma16(qf[kk], kf, s[ct]);
      }
    }
    // ---- scale + causal mask ----
    const bool maskb = (kb + 63 > qb);
    #pragma unroll
    for (int ct = 0; ct < 4; ++ct){
      const int key = kb + ct*16 + l15;
      #pragma unroll
      for (int r = 0; r < 4; ++r){
        float sv = s[ct][r] * 0.125f;
        if (maskb && key > (qb + lg*4 + r)) sv = -3.0e38f;
        s[ct][r] = sv;
      }
    }
    // ---- online softmax ----
    float sc[4];
    #pragma unroll
    for (int r = 0; r < 4; ++r){
      float v = fmaxf(fmaxf(s[0][r], s[1][r]), fmaxf(s[2][r], s[3][r]));
      #pragma unroll
      for (int off = 1; off < 16; off <<= 1) v = fmaxf(v, __shfl_xor(v, off));
      const float mn = fmaxf(m[r], v);
      sc[r] = __expf(m[r] - mn);
      m[r] = mn;
    }
    float rs[4] = {0.f, 0.f, 0.f, 0.f};
    #pragma unroll
    for (int ct = 0; ct < 4; ++ct)
      #pragma unroll
      for (int r = 0; r < 4; ++r){
        const float p = __expf(s[ct][r] - m[r]);
        s[ct][r] = p;
        rs[r] += p;
      }
    #pragma unroll
    for (int r = 0; r < 4; ++r){
      float v = rs[r];
      #pragma unroll
      for (int off = 1; off < 16; off <<= 1) v += __shfl_xor(v, off);
      l[r] = l[r]*sc[r] + v;
    }
    #pragma unroll
    for (int dt = 0; dt < 4; ++dt)
      #pragma unroll
      for (int r = 0; r < 4; ++r) o[dt][r] *= sc[r];

    // ---- P (C-layout) -> per-wave swizzled LDS -> A-fragment ----
    char* Pb = (char*)&P[w][0];
    #pragma unroll
    for (int ct = 0; ct < 4; ++ct)
      #pragma unroll
      for (int r = 0; r < 4; ++r){
        const int row = lg*4 + r;
        const int cb  = (ct*32 + l15*2) ^ ((row & 7) << 4);
        *(u16*)(Pb + row*128 + cb) = f2bf(s[ct][r]);
      }
    asm volatile("s_waitcnt lgkmcnt(0)" ::: "memory");
    bf16x8 pf[2];
    {
      const int swzp = (l15 & 7) << 4;
      #pragma unroll
      for (int kk = 0; kk < 2; ++kk)
        pf[kk] = *(const bf16x8*)(Pb + l15*128 + ((kk*64 + lg*16) ^ swzp));
    }
    // ---- O += P V ----
    const char* Vb = (const char*)&Vs[cur][0];
    #pragma unroll
    for (int dt = 0; dt < 4; ++dt){
      const int d = dt*16 + l15;
      const int swz = (d & 7) << 4;
      #pragma unroll
      for (int kk = 0; kk < 2; ++kk){
        bf16x8 vf = *(const bf16x8*)(Vb + d*128 + ((kk*64 + lg*16) ^ swz));
        o[dt] = mfma16(pf[kk], vf, o[dt]);
      }
    }
    if (ib + 1 < nt){
      asm volatile("s_waitcnt vmcnt(0)" ::: "memory");
      __syncthreads();
      cur ^= 1;
    }
  }

  float inv[4];
  #pragma unroll
  for (int r = 0; r < 4; ++r) inv[r] = 1.0f / l[r];
  #pragma unroll
  for (int dt = 0; dt < 4; ++dt)
    #pragma unroll
    for (int r = 0; r < 4; ++r)
      ao[(size_t)(qb + lg*4 + r)*1024 + h*64 + dt*16 + l15] = f2bf(o[dt][r] * inv[r]);
}

// ---------- launch ----------
extern "C" void kernel_launch(void* const* d_in, const int* in_sizes, int n_in,
                              void* d_out, int out_size, void* d_ws, size_t ws_size,
                              hipStream_t stream) {
  const float* x  = (const float*)d_in[0];   // (1,2048,1024)
  const float* wq = (const float*)d_in[1];   // (3072,1024)
  const float* wo = (const float*)d_in[2];   // (1024,1024)
  float* out = (float*)d_out;                // (1,2048,1024) fp32

  char* w = (char*)d_ws;                     // 44 MB used
  u16*   xb  = (u16*)(w + (size_t) 0);        // 4 MB  x bf16
  u16*   wqb = (u16*)(w + (size_t)( 4<<20));  // 6 MB  Wqkv bf16
  u16*   wob = (u16*)(w + (size_t)(10<<20));  // 2 MB  Wout bf16
  u16*   q_r = (u16*)(w + (size_t)(12<<20));  // 4 MB  q roped bf16 [16][2048][64]
  u16*   k_r = (u16*)(w + (size_t)(16<<20));  // 4 MB  k roped bf16 [16][2048][64]
  u16*   v_t = (u16*)(w + (size_t)(20<<20));  // 4 MB  v bf16 transposed [16][64][2048]
  u16*   ao  = (u16*)(w + (size_t)(24<<20));  // 4 MB  attn out bf16 [2048][1024]
  float* qkf = (float*)(w + (size_t)(28<<20)); // 16 MB q,k fp32 [2][16][2048][64]

  convert_kernel<<<2048, 256, 0, stream>>>(x, wq, wo, xb, wqb, wob);
  gemm_bt<1><<<dim3(24, 16), 512, 0, stream>>>(xb, wqb, 1024, nullptr, 0, v_t, qkf);
  rope_kernel<<<8192, 256, 0, stream>>>(qkf, q_r, k_r);
  attn_kernel<<<dim3(32, 16), 256, 0, stream>>>(q_r, k_r, v_t, ao);
  gemm_bt<0><<<dim3(8, 16), 512, 0, stream>>>(ao, wob, 1024, out, 1024, nullptr, nullptr);
}

// Round 6
// 169.512 us; speedup vs baseline: 1.5187x; 1.1166x over previous
//
#include <hip/hip_runtime.h>

#define DEVI __device__ __forceinline__

typedef __bf16 bf16x8 __attribute__((ext_vector_type(8)));
typedef float  f32x4  __attribute__((ext_vector_type(4)));
typedef unsigned short u16;

// ---------- helpers ----------
static DEVI u16 f2bf(float f){                 // fp32 -> bf16 RNE
  unsigned u = __builtin_bit_cast(unsigned, f);
  u += 0x7fffu + ((u >> 16) & 1u);
  return (u16)(u >> 16);
}

static DEVI f32x4 mfma16(bf16x8 a, bf16x8 b, f32x4 c){
  return __builtin_amdgcn_mfma_f32_16x16x32_bf16(a, b, c, 0, 0, 0);
}

static DEVI void gload_lds16(const void* g, void* l){
  __builtin_amdgcn_global_load_lds((const __attribute__((address_space(1))) unsigned int*)g,
                                   (__attribute__((address_space(3))) unsigned int*)l,
                                   16, 0, 0);
}

// ---------- 1) fp32 -> bf16 conversion of x, Wqkv, Wout ----------
__global__ void convert_kernel(const float* __restrict__ x, const float* __restrict__ wq,
                               const float* __restrict__ wo,
                               u16* __restrict__ xb, u16* __restrict__ wqb, u16* __restrict__ wob){
  const int NX = 2048*1024, NQ = 3072*1024, NW = 1024*1024;
  const int total4 = (NX + NQ + NW) / 4;
  for (int i = blockIdx.x*blockDim.x + threadIdx.x; i < total4; i += gridDim.x*blockDim.x){
    int e = i * 4;
    const float* src; u16* dst; int off;
    if (e < NX)           { src = x;  dst = xb;  off = e; }
    else if (e < NX + NQ) { src = wq; dst = wqb; off = e - NX; }
    else                  { src = wo; dst = wob; off = e - NX - NQ; }
    float4 v = *(const float4*)(src + off);
    ushort4 o;
    o.x = f2bf(v.x); o.y = f2bf(v.y); o.z = f2bf(v.z); o.w = f2bf(v.w);
    *(ushort4*)(dst + off) = o;
  }
}

// ---------- 2/5) GEMM  C[M,N] = A[M,K] * B[N,K]^T  (bf16 in, fp32 acc) ----------
template<int EPI>
__global__ __launch_bounds__(512, 1)
void gemm_bt(const u16* __restrict__ A, const u16* __restrict__ B, int K,
             float* __restrict__ C, int ldc,
             u16* __restrict__ v_t, float* __restrict__ qkf){
  __shared__ u16 As[128*64];
  __shared__ u16 Bs[128*64];
  const int tid  = threadIdx.x;
  const int lane = tid & 63;
  const int wid  = tid >> 6;
  const int wr   = wid >> 2, wc = wid & 3;      // wave -> 64x32 sub-tile
  const int l15  = lane & 15, lg = lane >> 4;
  const int bm   = blockIdx.y * 128, bn = blockIdx.x * 128;

  const int c0 = tid, c1 = tid + 512;
  const int r0 = c0 >> 3, r1 = c1 >> 3;
  const int gb0 = ((c0 & 7) << 4) ^ ((r0 & 7) << 4);
  const int gb1 = ((c1 & 7) << 4) ^ ((r1 & 7) << 4);
  const u16* Ag0 = A + (size_t)(bm + r0) * K + (gb0 >> 1);
  const u16* Ag1 = A + (size_t)(bm + r1) * K + (gb1 >> 1);
  const u16* Bg0 = B + (size_t)(bn + r0) * K + (gb0 >> 1);
  const u16* Bg1 = B + (size_t)(bn + r1) * K + (gb1 >> 1);

  int baseA[4], swzA[4], baseB[2], swzB[2];
  #pragma unroll
  for (int m = 0; m < 4; ++m){
    int r = wr*64 + m*16 + l15;
    baseA[m] = r * 128; swzA[m] = (r & 7) << 4;
  }
  #pragma unroll
  for (int n = 0; n < 2; ++n){
    int r = wc*32 + n*16 + l15;
    baseB[n] = r * 128; swzB[n] = (r & 7) << 4;
  }
  const int colb = lg * 16;

  f32x4 acc[4][2] = {};
  const char* Ab = (const char*)As;
  const char* Bb = (const char*)Bs;

  for (int kb = 0; kb < K; kb += 64){
    gload_lds16(Ag0 + kb, &As[c0 * 8]);
    gload_lds16(Ag1 + kb, &As[c1 * 8]);
    gload_lds16(Bg0 + kb, &Bs[c0 * 8]);
    gload_lds16(Bg1 + kb, &Bs[c1 * 8]);
    __syncthreads();
    #pragma unroll
    for (int kk = 0; kk < 2; ++kk){
      bf16x8 av[4], bv[2];
      #pragma unroll
      for (int m = 0; m < 4; ++m)
        av[m] = *(const bf16x8*)(Ab + baseA[m] + ((kk*64 + colb) ^ swzA[m]));
      #pragma unroll
      for (int n = 0; n < 2; ++n)
        bv[n] = *(const bf16x8*)(Bb + baseB[n] + ((kk*64 + colb) ^ swzB[n]));
      #pragma unroll
      for (int m = 0; m < 4; ++m)
        #pragma unroll
        for (int n = 0; n < 2; ++n)
          acc[m][n] = mfma16(av[m], bv[n], acc[m][n]);
    }
    __syncthreads();
  }

  #pragma unroll
  for (int m = 0; m < 4; ++m){
    const int srow = bm + wr*64 + m*16 + lg*4;
    #pragma unroll
    for (int n = 0; n < 2; ++n){
      const int f = bn + wc*32 + n*16 + l15;
      f32x4 v = acc[m][n];
      if (EPI == 0){
        #pragma unroll
        for (int r = 0; r < 4; ++r)
          C[(size_t)(srow + r)*ldc + f] = v[r];
      } else {
        const int which = f >> 10, rem = f & 1023;
        const int h = rem >> 6, d = rem & 63;
        if (which == 2){
          ushort4 p;
          p.x = f2bf(v[0]); p.y = f2bf(v[1]); p.z = f2bf(v[2]); p.w = f2bf(v[3]);
          *(ushort4*)(v_t + ((size_t)(h*64 + d))*2048 + srow) = p;
        } else {
          float* dst = qkf + (((size_t)(which*16 + h))*2048 + srow)*64 + d;
          #pragma unroll
          for (int r = 0; r < 4; ++r) dst[(size_t)r * 64] = v[r];
        }
      }
    }
  }
}

// ---------- 3) RoPE on q,k (fp32 in, bf16 out) ----------
__global__ void rope_kernel(const float* __restrict__ qkf,
                            u16* __restrict__ q_r, u16* __restrict__ k_r){
  const int t = blockIdx.x*blockDim.x + threadIdx.x;   // 2^21 threads exactly
  const int i = t & 31;
  const int s = (t >> 5) & 2047;
  const int h = (t >> 16) & 15;
  const int w = t >> 20;
  const float2 xv = *(const float2*)(qkf + (((size_t)w*16 + h)*2048 + s)*64 + 2*i);
  const int idx0 = (2*i) & 31;
  const float NEGL = -0.41524101186091903f;            // -log2(10000)/32
  const float f0 = exp2f(NEGL * (float)idx0);
  const float f1 = exp2f(NEGL * (float)(idx0 + 1));
  const float a0 = (float)s * f0, a1 = (float)s * f1;
  float s0, c0, s1, c1;
  sincosf(a0, &s0, &c0);
  sincosf(a1, &s1, &c1);
  const float o0 = xv.x * c0 - xv.y * s0;
  const float o1 = xv.y * c1 + xv.x * s1;
  u16* dst = (w == 0 ? q_r : k_r) + ((size_t)h*2048 + s)*64 + 2*i;
  ushort2 pr; pr.x = f2bf(o0); pr.y = f2bf(o1);
  *(ushort2*)dst = pr;
}

// ---------- 4) causal flash attention v2 ----------
// 4 waves/block, QBLK=64, KB=128. K/V double-buffered in LDS via
// global_load_lds (XOR-swizzled). Heads pinned to XCDs (K/V L2-resident).
// Per-lane l partials (single end reduce). Longest tiles first per XCD.
static DEVI void stage_kv128(const u16* __restrict__ kg, const u16* __restrict__ vg,
                             u16* Ks, u16* Vs, int tid){
  #pragma unroll
  for (int i = 0; i < 4; ++i){
    const int c = tid + i*256;                 // 0..1023
    const int kr = c >> 3;                     // K row (key) 0..127
    const int kc = ((c & 7) << 4) ^ ((kr & 7) << 4);
    gload_lds16(kg + (size_t)kr*64 + (kc >> 1), Ks + c*8);
    const int vr = c >> 4;                     // V row (d) 0..63
    const int vc = ((c & 15) << 4) ^ ((vr & 7) << 4);
    gload_lds16(vg + (size_t)vr*2048 + (vc >> 1), Vs + c*8);
  }
}

__global__ __launch_bounds__(256)
void attn_kernel(const u16* __restrict__ q_r, const u16* __restrict__ k_r,
                 const u16* __restrict__ v_t, u16* __restrict__ ao){
  __shared__ u16 Ks[2][128*64];   // 32 KB  [key][d] swizzled
  __shared__ u16 Vs[2][64*128];   // 32 KB  [d][key] swizzled
  __shared__ u16 P[4][16*128];    // 16 KB  per-wave
  const int tid  = threadIdx.x;
  const int lane = tid & 63, w = tid >> 6;
  const int l15  = lane & 15, lg = lane >> 4;
  // XCD-pinned mapping: bid%8 = XCD (round-robin dispatch); one hot head
  // per XCD at a time so its 0.5 MB K/V stays L2-resident.
  const int bid  = blockIdx.x;
  const int xcd  = bid & 7, j = bid >> 3;      // j: 0..63
  const int h    = xcd + ((j >= 32) ? 8 : 0);
  const int tile = 31 - (j & 31);              // longest first
  const int q0   = tile * 64;
  const int qb   = q0 + w*16;                  // wave's q-row base
  const int nt   = (tile >> 1) + 1;            // number of 128-key tiles

  const u16* kg = k_r + (size_t)h*2048*64;
  const u16* vg = v_t + (size_t)h*64*2048;

  bf16x8 qf[2];
  #pragma unroll
  for (int kk = 0; kk < 2; ++kk)
    qf[kk] = *(const bf16x8*)(q_r + ((size_t)h*2048 + qb + l15)*64 + kk*32 + lg*8);

  f32x4 o[4] = {};
  float m[4], l[4];
  #pragma unroll
  for (int r = 0; r < 4; ++r){ m[r] = -3.0e38f; l[r] = 0.f; }

  stage_kv128(kg, vg, &Ks[0][0], &Vs[0][0], tid);
  asm volatile("s_waitcnt vmcnt(0)" ::: "memory");
  __syncthreads();

  int cur = 0;
  for (int ib = 0; ib < nt; ++ib){
    const int kb = ib * 128;
    if (ib + 1 < nt)
      stage_kv128(kg + (size_t)(kb + 128)*64, vg + (kb + 128), &Ks[cur^1][0], &Vs[cur^1][0], tid);

    // ---- S = Q K^T (16 q-rows x 128 keys) ----
    f32x4 s[8];
    const char* Kb = (const char*)&Ks[cur][0];
    #pragma unroll
    for (int ct = 0; ct < 8; ++ct){
      s[ct] = f32x4{0.f, 0.f, 0.f, 0.f};
      const int row = ct*16 + l15;
      const int swz = (row & 7) << 4;
      #pragma unroll
      for (int kk = 0; kk < 2; ++kk){
        bf16x8 kf = *(const bf16x8*)(Kb + row*128 + ((kk*64 + lg*16) ^ swz));
        s[ct] = mfma16(qf[kk], kf, s[ct]);
      }
    }
    // ---- scale + causal mask ----
    const bool maskb = (kb + 127 > qb);
    #pragma unroll
    for (int ct = 0; ct < 8; ++ct){
      const int key = kb + ct*16 + l15;
      #pragma unroll
      for (int r = 0; r < 4; ++r){
        float sv = s[ct][r] * 0.125f;
        if (maskb && key > (qb + lg*4 + r)) sv = -3.0e38f;
        s[ct][r] = sv;
      }
    }
    // ---- online softmax (max reduce only; l kept as per-lane partials) ----
    float sc[4];
    #pragma unroll
    for (int r = 0; r < 4; ++r){
      float v = s[0][r];
      #pragma unroll
      for (int ct = 1; ct < 8; ++ct) v = fmaxf(v, s[ct][r]);
      #pragma unroll
      for (int off = 1; off < 16; off <<= 1) v = fmaxf(v, __shfl_xor(v, off));
      const float mn = fmaxf(m[r], v);
      sc[r] = __expf(m[r] - mn);
      m[r] = mn;
    }
    float rs[4] = {0.f, 0.f, 0.f, 0.f};
    #pragma unroll
    for (int ct = 0; ct < 8; ++ct)
      #pragma unroll
      for (int r = 0; r < 4; ++r){
        const float p = __expf(s[ct][r] - m[r]);
        s[ct][r] = p;
        rs[r] += p;
      }
    #pragma unroll
    for (int r = 0; r < 4; ++r) l[r] = l[r]*sc[r] + rs[r];
    #pragma unroll
    for (int dt = 0; dt < 4; ++dt)
      #pragma unroll
      for (int r = 0; r < 4; ++r) o[dt][r] *= sc[r];

    // ---- P (C-layout) -> per-wave swizzled LDS -> A-fragment ----
    char* Pb = (char*)&P[w][0];
    #pragma unroll
    for (int ct = 0; ct < 8; ++ct)
      #pragma unroll
      for (int r = 0; r < 4; ++r){
        const int row = lg*4 + r;
        const int cb  = (ct*32 + l15*2) ^ ((row & 7) << 4);
        *(u16*)(Pb + row*256 + cb) = f2bf(s[ct][r]);
      }
    asm volatile("s_waitcnt lgkmcnt(0)" ::: "memory");
    bf16x8 pf[4];
    {
      const int swzp = (l15 & 7) << 4;
      #pragma unroll
      for (int kk = 0; kk < 4; ++kk)
        pf[kk] = *(const bf16x8*)(Pb + l15*256 + ((kk*64 + lg*16) ^ swzp));
    }
    // ---- O += P V ----
    const char* Vb = (const char*)&Vs[cur][0];
    #pragma unroll
    for (int dt = 0; dt < 4; ++dt){
      const int d = dt*16 + l15;
      const int swz = (d & 7) << 4;
      #pragma unroll
      for (int kk = 0; kk < 4; ++kk){
        bf16x8 vf = *(const bf16x8*)(Vb + d*256 + ((kk*64 + lg*16) ^ swz));
        o[dt] = mfma16(pf[kk], vf, o[dt]);
      }
    }
    if (ib + 1 < nt){
      asm volatile("s_waitcnt vmcnt(0)" ::: "memory");
      __syncthreads();
      cur ^= 1;
    }
  }

  float inv[4];
  #pragma unroll
  for (int r = 0; r < 4; ++r){
    float v = l[r];
    #pragma unroll
    for (int off = 1; off < 16; off <<= 1) v += __shfl_xor(v, off);
    inv[r] = 1.0f / v;
  }
  #pragma unroll
  for (int dt = 0; dt < 4; ++dt)
    #pragma unroll
    for (int r = 0; r < 4; ++r)
      ao[(size_t)(qb + lg*4 + r)*1024 + h*64 + dt*16 + l15] = f2bf(o[dt][r] * inv[r]);
}

// ---------- launch ----------
extern "C" void kernel_launch(void* const* d_in, const int* in_sizes, int n_in,
                              void* d_out, int out_size, void* d_ws, size_t ws_size,
                              hipStream_t stream) {
  const float* x  = (const float*)d_in[0];   // (1,2048,1024)
  const float* wq = (const float*)d_in[1];   // (3072,1024)
  const float* wo = (const float*)d_in[2];   // (1024,1024)
  float* out = (float*)d_out;                // (1,2048,1024) fp32

  char* w = (char*)d_ws;                     // 44 MB used
  u16*   xb  = (u16*)(w + (size_t) 0);        // 4 MB  x bf16
  u16*   wqb = (u16*)(w + (size_t)( 4<<20));  // 6 MB  Wqkv bf16
  u16*   wob = (u16*)(w + (size_t)(10<<20));  // 2 MB  Wout bf16
  u16*   q_r = (u16*)(w + (size_t)(12<<20));  // 4 MB  q roped bf16 [16][2048][64]
  u16*   k_r = (u16*)(w + (size_t)(16<<20));  // 4 MB  k roped bf16 [16][2048][64]
  u16*   v_t = (u16*)(w + (size_t)(20<<20));  // 4 MB  v bf16 transposed [16][64][2048]
  u16*   ao  = (u16*)(w + (size_t)(24<<20));  // 4 MB  attn out bf16 [2048][1024]
  float* qkf = (float*)(w + (size_t)(28<<20)); // 16 MB q,k fp32 [2][16][2048][64]

  convert_kernel<<<2048, 256, 0, stream>>>(x, wq, wo, xb, wqb, wob);
  gemm_bt<1><<<dim3(24, 16), 512, 0, stream>>>(xb, wqb, 1024, nullptr, 0, v_t, qkf);
  rope_kernel<<<8192, 256, 0, stream>>>(qkf, q_r, k_r);
  attn_kernel<<<512, 256, 0, stream>>>(q_r, k_r, v_t, ao);
  gemm_bt<0><<<dim3(8, 16), 512, 0, stream>>>(ao, wob, 1024, out, 1024, nullptr, nullptr);
}